// Round 16
// baseline (5206.015 us; speedup 1.0000x reference)
//
#include <hip/hip_runtime.h>

#define H 64
#define T_STEPS 2048

typedef _Float16 f16x8 __attribute__((ext_vector_type(8)));
typedef float    f32x4 __attribute__((ext_vector_type(4)));

__device__ __forceinline__ float sigmoid_f(float x) {
    return 1.0f / (1.0f + __expf(-x));
}
__device__ __forceinline__ float tanh_f(float x) {
    return 2.0f / (1.0f + __expf(-2.0f * x)) - 1.0f;
}

// 8 consecutive fp32 -> f16x8 (load-time only)
__device__ __forceinline__ f16x8 cvt8(const float* __restrict__ src) {
    const float4* p = (const float4*)src;
    float4 v0 = p[0], v1 = p[1];
    f16x8 r;
    r[0] = (_Float16)v0.x; r[1] = (_Float16)v0.y;
    r[2] = (_Float16)v0.z; r[3] = (_Float16)v0.w;
    r[4] = (_Float16)v1.x; r[5] = (_Float16)v1.y;
    r[6] = (_Float16)v1.z; r[7] = (_Float16)v1.w;
    return r;
}

// R16: MFMA LSTM. R13-R15 busy-cycle model: ALL f16 VALU MACs (dot2,
// fma_mix, pk_fma) are ~8cyc/wave64 slow-pipe -> R13 (2.4ms) is the f16-VALU
// roofline. The matrix pipe is idle (MfmaUtil=0) and co-schedules with VALU
// (m114). Move gate GEMMs to mfma_f32_16x16x32_f16, N=1 (batch/block),
// B broadcast (frag addr lane&15-independent).
// Row reorder: gate rows stored cell-major (rr = 4*cell + gate) so C/D map
// (row=4q+reg, col=lane&15 -- m89-verified) gives each lane the 4 gates of
// cell 4T+q in acc[0..3] -> per-lane cell update, no cross-lane ops.
// A map (guide m120): A[m=lane&15][k=q*8+j]; B[k=q*8+j][n=lane&15].
// 48 jobs (3 layers x 16 row-tiles) = 12 waves x 4; L0 A-frags live in LDS
// (32KB, built once) to keep register A-frags at <=12 chunks (48 VGPR),
// under the 768-thread allocator cap (~72-85, R13-measured).
__global__ __launch_bounds__(768)
void lstm3_mfma(const float* __restrict__ x,
                const float* __restrict__ Wih0, const float* __restrict__ Whh0,
                const float* __restrict__ bih0, const float* __restrict__ bhh0,
                const float* __restrict__ Wih1, const float* __restrict__ Whh1,
                const float* __restrict__ bih1, const float* __restrict__ bhh1,
                const float* __restrict__ Wih2, const float* __restrict__ Whh2,
                const float* __restrict__ bih2, const float* __restrict__ bhh2,
                const float* __restrict__ Wout, const float* __restrict__ bout,
                float* __restrict__ out)
{
    __shared__ __align__(16) float xs[T_STEPS * 2];      // 16 KB input seq
    __shared__ __align__(16) f16x8 l0a[16 * 2 * 64];     // 32 KB L0 A-frags
    __shared__ __align__(16) float biasr[3 * 256];       // 3 KB reordered bias
    __shared__ __align__(16) float wxr[512];             // 2 KB reordered Wih0
    __shared__ __align__(16) _Float16 hb0[2][H];         // h double buffers
    __shared__ __align__(16) _Float16 hb1[2][H];
    __shared__ __align__(16) _Float16 hb2[2][H];
    __shared__ __align__(16) float h2f[H];               // fp32 h2 (projection)

    const int tid  = threadIdx.x;
    const int b    = blockIdx.x;
    const int wave = tid >> 6;
    const int lane = tid & 63;
    const int n    = lane & 15;      // MFMA col / A-row lane index
    const int q    = lane >> 4;      // quad

    // ---- stage x (1024 float4) ----
    {
        const float4* xsrc = (const float4*)(x + (size_t)b * T_STEPS * 2);
        ((float4*)xs)[tid] = xsrc[tid];
        if (tid < 256) ((float4*)xs)[tid + 768] = xsrc[tid + 768];
    }
    // ---- reordered biases: biasr[lay*256 + cell*4 + gate] ----
    {
        const int lay = tid >> 8, rr = tid & 255;
        const int gate = rr & 3, cell = rr >> 2;
        const float* bi = (lay == 0) ? bih0 : (lay == 1) ? bih1 : bih2;
        const float* bh = (lay == 0) ? bhh0 : (lay == 1) ? bhh1 : bhh2;
        biasr[tid] = bi[gate * 64 + cell] + bh[gate * 64 + cell];
    }
    // ---- reordered Wih0: wxr[cell*8 + gate*2 + j] ----
    if (tid < 512) {
        const int cell = tid >> 3, rem = tid & 7;
        const int gate = rem >> 1, j = rem & 1;
        wxr[tid] = Wih0[(gate * 64 + cell) * 2 + j];
    }
    // ---- L0 A-frags into LDS: frag (T,c) lane ln: A[m=16T+(ln&15)][k=32c+(ln>>4)*8+e] ----
    for (int i = tid; i < 2048; i += 768) {
        const int T = i >> 7, rem = i & 127;
        const int c = rem >> 6, ln = rem & 63;
        const int nn = ln & 15, qq = ln >> 4;
        const int srcrow = (nn & 3) * 64 + 4 * T + (nn >> 2);
        l0a[i] = cvt8(Whh0 + srcrow * 64 + 32 * c + qq * 8);
    }
    // ---- register A-frags (L1/L2 jobs), 3 wave-uniform variants ----
    f16x8 c0, c1, c2, c3, c4, c5, c6, c7, c8, c9, c10, c11;
    {
        const int srow4 = (n & 3) * 64 + (n >> 2);   // + 4*T per tile
        auto ldA = [&](const float* Mih, const float* Mhh, int T,
                       f16x8& A0, f16x8& A1, f16x8& A2, f16x8& A3) {
            const int sr = srow4 + 4 * T;
            A0 = cvt8(Mih + sr * 64 + q * 8);
            A1 = cvt8(Mih + sr * 64 + 32 + q * 8);
            A2 = cvt8(Mhh + sr * 64 + q * 8);
            A3 = cvt8(Mhh + sr * 64 + 32 + q * 8);
        };
        f16x8 z = {};
        c8 = z; c9 = z; c10 = z; c11 = z;
        if (wave < 4) {
            ldA(Wih1, Whh1, wave + 8, c0, c1, c2, c3);
            ldA(Wih2, Whh2, wave + 4, c4, c5, c6, c7);
        } else if (wave < 8) {
            ldA(Wih1, Whh1, wave - 4, c0, c1, c2, c3);
            ldA(Wih1, Whh1, wave + 8, c4, c5, c6, c7);
            ldA(Wih2, Whh2, wave + 4, c8, c9, c10, c11);
        } else {
            ldA(Wih1, Whh1, wave - 4, c0, c1, c2, c3);
            ldA(Wih2, Whh2, wave - 8, c4, c5, c6, c7);
            ldA(Wih2, Whh2, wave + 4, c8, c9, c10, c11);
        }
    }
    asm volatile("" : "+v"(c0), "+v"(c1), "+v"(c2));
    asm volatile("" : "+v"(c3), "+v"(c4), "+v"(c5));
    asm volatile("" : "+v"(c6), "+v"(c7), "+v"(c8));
    asm volatile("" : "+v"(c9), "+v"(c10), "+v"(c11));

    if (tid < H) {
        _Float16 z = (_Float16)0.f;
        hb0[0][tid] = z; hb0[1][tid] = z;
        hb1[0][tid] = z; hb1[1][tid] = z;
        hb2[0][tid] = z; hb2[1][tid] = z;
        h2f[tid] = 0.f;
    }
    float cA = 0.f, cB = 0.f, cC = 0.f, cD = 0.f;   // cell states (per job)
    __syncthreads();

#pragma unroll 1
    for (int p = 0; p < T_STEPS + 2; ++p) {
        const int s  = (p + 1) & 1;
        const int ws = p & 1;
        const bool on0 = (p < T_STEPS);
        const bool on1 = (p >= 1) && (p <= T_STEPS);
        const bool on2 = (p >= 2);

        // per-lane cell update from acc = {i,f,g,o} preacts
        auto update = [&](f32x4 acc, float& cs, _Float16* hout, bool isl2) {
            float gi = sigmoid_f(acc[0]);
            float gf = sigmoid_f(acc[1]);
            float gg = tanh_f(acc[2]);
            float go = sigmoid_f(acc[3]);
            cs = gf * cs + gi * gg;
            float hh = go * tanh_f(cs);
            if (n == 0) {
                const int cq = 0;  (void)cq;
                hout[0] = (_Float16)hh;          // hout pre-offset to cell
                if (isl2) h2f[(int)(hout - hb2[ws])] = hh;
            }
        };

        auto jobL0 = [&](int T, float& cs) {
            if (!on0) return;
            const int cq = 4 * T + q;
            f32x4 acc = *(const f32x4*)&biasr[cq * 4];
            f16x8 a0 = l0a[(T * 2 + 0) * 64 + lane];
            f16x8 a1 = l0a[(T * 2 + 1) * 64 + lane];
            f16x8 b0 = *(const f16x8*)&hb0[s][q * 8];
            f16x8 b1 = *(const f16x8*)&hb0[s][32 + q * 8];
            acc = __builtin_amdgcn_mfma_f32_16x16x32_f16(a0, b0, acc, 0, 0, 0);
            acc = __builtin_amdgcn_mfma_f32_16x16x32_f16(a1, b1, acc, 0, 0, 0);
            float2 xt = *(const float2*)&xs[2 * p];
            f32x4 wa = *(const f32x4*)&wxr[cq * 8];
            f32x4 wb = *(const f32x4*)&wxr[cq * 8 + 4];
            acc[0] += wa[0] * xt.x + wa[1] * xt.y;
            acc[1] += wa[2] * xt.x + wa[3] * xt.y;
            acc[2] += wb[0] * xt.x + wb[1] * xt.y;
            acc[3] += wb[2] * xt.x + wb[3] * xt.y;
            update(acc, cs, &hb0[ws][cq], false);
        };

        auto jobL12 = [&](int lay, int T, bool onf,
                          f16x8 A0, f16x8 A1, f16x8 A2, f16x8 A3,
                          const _Float16* hlo, const _Float16* hhi,
                          _Float16* hob, float& cs) {
            if (!onf) return;
            const int cq = 4 * T + q;
            f32x4 acc = *(const f32x4*)&biasr[lay * 256 + cq * 4];
            f16x8 b0 = *(const f16x8*)&hlo[q * 8];
            f16x8 b1 = *(const f16x8*)&hlo[32 + q * 8];
            f16x8 b2 = *(const f16x8*)&hhi[q * 8];
            f16x8 b3 = *(const f16x8*)&hhi[32 + q * 8];
            acc = __builtin_amdgcn_mfma_f32_16x16x32_f16(A0, b0, acc, 0, 0, 0);
            acc = __builtin_amdgcn_mfma_f32_16x16x32_f16(A1, b1, acc, 0, 0, 0);
            acc = __builtin_amdgcn_mfma_f32_16x16x32_f16(A2, b2, acc, 0, 0, 0);
            acc = __builtin_amdgcn_mfma_f32_16x16x32_f16(A3, b3, acc, 0, 0, 0);
            update(acc, cs, &hob[cq], lay == 2);
        };

        if (wave < 4) {
            jobL0(wave, cA);
            jobL0(wave + 12, cB);
            jobL12(1, wave + 8, on1, c0, c1, c2, c3, hb0[s], hb1[s], hb1[ws], cC);
            jobL12(2, wave + 4, on2, c4, c5, c6, c7, hb1[s], hb2[s], hb2[ws], cD);
        } else if (wave < 8) {
            jobL0(wave, cA);
            jobL12(1, wave - 4, on1, c0, c1, c2, c3, hb0[s], hb1[s], hb1[ws], cB);
            jobL12(1, wave + 8, on1, c4, c5, c6, c7, hb0[s], hb1[s], hb1[ws], cC);
            jobL12(2, wave + 4, on2, c8, c9, c10, c11, hb1[s], hb2[s], hb2[ws], cD);
        } else {
            jobL0(wave, cA);
            jobL12(1, wave - 4, on1, c0, c1, c2, c3, hb0[s], hb1[s], hb1[ws], cB);
            jobL12(2, wave - 8, on2, c4, c5, c6, c7, hb1[s], hb2[s], hb2[ws], cC);
            jobL12(2, wave + 4, on2, c8, c9, c10, c11, hb1[s], hb2[s], hb2[ws], cD);
        }
        __syncthreads();
    }

    // ---- fused projection: out[b,:] = h2_last @ Wout^T + bout ----
    if (tid < 11) {
        float acc = bout[tid];
#pragma unroll
        for (int jj = 0; jj < H; ++jj)
            acc += Wout[tid * H + jj] * h2f[jj];
        out[b * 11 + tid] = acc;
    }
}

extern "C" void kernel_launch(void* const* d_in, const int* in_sizes, int n_in,
                              void* d_out, int out_size, void* d_ws, size_t ws_size,
                              hipStream_t stream) {
    const float* x    = (const float*)d_in[0];
    const float* Wih0 = (const float*)d_in[1];
    const float* Whh0 = (const float*)d_in[2];
    const float* bih0 = (const float*)d_in[3];
    const float* bhh0 = (const float*)d_in[4];
    const float* Wih1 = (const float*)d_in[5];
    const float* Whh1 = (const float*)d_in[6];
    const float* bih1 = (const float*)d_in[7];
    const float* bhh1 = (const float*)d_in[8];
    const float* Wih2 = (const float*)d_in[9];
    const float* Whh2 = (const float*)d_in[10];
    const float* bih2 = (const float*)d_in[11];
    const float* bhh2 = (const float*)d_in[12];
    const float* Wout = (const float*)d_in[13];
    const float* bout = (const float*)d_in[14];
    float* out = (float*)d_out;

    lstm3_mfma<<<256, 768, 0, stream>>>(x,
        Wih0, Whh0, bih0, bhh0,
        Wih1, Whh1, bih1, bhh1,
        Wih2, Whh2, bih2, bhh2,
        Wout, bout, out);
}